// Round 14
// baseline (1864.861 us; speedup 1.0000x reference)
//
#include <hip/hip_runtime.h>
#include <hip/hip_fp16.h>

// RaBitQ forward, two kernels.
// x: 262144 vectors of D=128 fp32. P: 128x128 fp32 orthonormal.
// out f32 concat: x_hat[262144*128] | packed[262144*16] | norms16[262144] | x016[262144]
//
// Kernel A (quantize): R8 numerics, delivery rebuilt:
//   - P in LDS as PAIR-ROWS: chunk (p,c) = {P[p][2c],P[p+64][2c],P[p][2c+1],
//     P[p+64][2c+1]}, XOR-swizzled (c^(p&7)), conflict-free b128 gathers.
//     One read feeds v_pk_fma_f32 for BOTH e=lane and e=lane+64 -> FMA count
//     halves (1024 pk_fma/pass); each half keeps its own ascending-d
//     sequential fmaf chain == BIT-IDENTICAL signs to R8.
//   - x via v_readlane from per-lane coalesced VGPRs (R13-proven mapping,
//     jo/v fully unrolled -> immediate lane idx). x-broadcasts leave the LDS
//     pipe entirely (R8: 256 of 320 b128/pass were x).
//   - 512-thr block, 64K LDS only -> 2 blocks/CU = 4 waves/SIMD, VGPR<=128.
//   - reduce: DPP wave_sum (R9/R10-proven), 2 LDS ops/vec instead of 12.
// Kernel B (dequantize): R8 kernel VERBATIM (proven, ~45us).

#define NVEC_TOTAL (4 * 16 * 4096)

typedef short short8 __attribute__((ext_vector_type(8)));
typedef float f32x2 __attribute__((ext_vector_type(2)));
typedef float f32x4 __attribute__((ext_vector_type(4)));
typedef unsigned int u32x4v __attribute__((ext_vector_type(4)));
typedef unsigned long long ull;

__device__ __forceinline__ float rfl_f(float v) {
  return __int_as_float(__builtin_amdgcn_readfirstlane(__float_as_int(v)));
}

__device__ __forceinline__ float rdlane_f(float v, int srclane) {
  return __int_as_float(__builtin_amdgcn_readlane(__float_as_int(v), srclane));
}

__device__ __forceinline__ ull sel8_u64(const ull* a, int s) {
  ull r0 = (s & 1) ? a[1] : a[0];
  ull r1 = (s & 1) ? a[3] : a[2];
  ull r2 = (s & 1) ? a[5] : a[4];
  ull r3 = (s & 1) ? a[7] : a[6];
  ull r4 = (s & 2) ? r1 : r0;
  ull r5 = (s & 2) ? r3 : r2;
  return (s & 4) ? r5 : r4;
}

__device__ __forceinline__ float sel8_f(const float* a, int s) {
  float r0 = (s & 1) ? a[1] : a[0];
  float r1 = (s & 1) ? a[3] : a[2];
  float r2 = (s & 1) ? a[5] : a[4];
  float r3 = (s & 1) ? a[7] : a[6];
  float r4 = (s & 2) ? r1 : r0;
  float r5 = (s & 2) ? r3 : r2;
  return (s & 4) ? r5 : r4;
}

template <int CTRL>
__device__ __forceinline__ float dpp_add(float v) {
  int t = __builtin_amdgcn_update_dpp(0, __float_as_int(v), CTRL, 0xF, 0xF, true);
  return v + __int_as_float(t);
}

// full 64-lane sum (R9/R10-proven): row_ror 1,2,4,8 (VALU) + xor16 + xor32
__device__ __forceinline__ float wave_sum(float v) {
  v = dpp_add<0x121>(v);
  v = dpp_add<0x122>(v);
  v = dpp_add<0x124>(v);
  v = dpp_add<0x128>(v);
  v += __int_as_float(__builtin_amdgcn_ds_swizzle(__float_as_int(v), 0x401F));
  v += __shfl_xor(v, 32);
  return v;
}

__device__ __forceinline__ unsigned short f2bf(float f) {  // fp32 -> bf16 RNE
  unsigned u = __float_as_uint(f);
  return (unsigned short)((u + 0x7FFFu + ((u >> 16) & 1u)) >> 16);
}

// ========================= Kernel A: quantize =========================
__global__ __launch_bounds__(512, 4) void rabitq_quant(const float* __restrict__ x,
                                                       const float* __restrict__ Pm,
                                                       float* __restrict__ out) {
  // pair-row P: 64 pair-rows x 64 chunks x 16B = 64 KiB
  __shared__ __align__(16) float Pp[64 * 256];

  const int tid = threadIdx.x;
  const int lane = tid & 63;
  const int ww = tid >> 6;

  // ---- stage P pair-rows, swizzled: chunk(p,c) at p*1024B + ((c^(p&7))*16B ----
  {
#pragma unroll
    for (int i = 0; i < 8; ++i) {
      const int s = tid + i * 512;     // chunk id 0..4095
      const int p = s >> 6, c = s & 63;
      const float2 a = *(const float2*)(Pm + (size_t)p * 128 + 2 * c);
      const float2 b = *(const float2*)(Pm + (size_t)(p + 64) * 128 + 2 * c);
      float4 w4; w4.x = a.x; w4.y = b.x; w4.z = a.y; w4.w = b.y;
      *(float4*)(&Pp[p * 256 + ((c ^ (p & 7)) << 2)]) = w4;
    }
  }
  __syncthreads();

  const int w = blockIdx.x * 8 + ww;  // global wave id, 0..8191
  float* const out_pack = out + (size_t)NVEC_TOTAL * 128;
  float* const out_norm = out_pack + (size_t)NVEC_TOTAL * 16;
  float* const out_x0   = out_norm + NVEC_TOTAL;

  const int sw1 = lane & 7;  // swizzle key for pair-row p = lane

#pragma unroll 1
  for (int t = 0; t < 4; ++t) {
    const int vbase = w * 32 + t * 8;

    // ---- per-lane coalesced x tile (R13-proven mapping):
    //      lane (v=lane&7, k=lane>>3) holds x[vbase+v][16k..16k+16) ----
    float xs[16];
    {
      const float* xb0 = x + (size_t)(vbase + (lane & 7)) * 128 + (lane >> 3) * 16;
      const float4 q0 = *(const float4*)(xb0 + 0);
      const float4 q1 = *(const float4*)(xb0 + 4);
      const float4 q2 = *(const float4*)(xb0 + 8);
      const float4 q3 = *(const float4*)(xb0 + 12);
      xs[0] = q0.x; xs[1] = q0.y; xs[2] = q0.z; xs[3] = q0.w;
      xs[4] = q1.x; xs[5] = q1.y; xs[6] = q1.z; xs[7] = q1.w;
      xs[8] = q2.x; xs[9] = q2.y; xs[10] = q2.z; xs[11] = q2.w;
      xs[12] = q3.x; xs[13] = q3.y; xs[14] = q3.z; xs[15] = q3.w;
    }

    // ---- x_rot = x @ P^T: pk_fma over pair-rows; x via readlane ----
    f32x2 acc2[8];
#pragma unroll
    for (int v = 0; v < 8; ++v) { acc2[v][0] = 0.f; acc2[v][1] = 0.f; }

#pragma unroll
    for (int jo = 0; jo < 8; ++jo) {
      // P chunks for c = 8*jo + ci : {P_lo[2c], P_hi[2c], P_lo[2c+1], P_hi[2c+1]}
      float4 pc[8];
#pragma unroll
      for (int ci = 0; ci < 8; ++ci) {
        const int c = 8 * jo + ci;
        pc[ci] = *(const float4*)(&Pp[lane * 256 + ((c ^ sw1) << 2)]);
      }
#pragma unroll
      for (int v = 0; v < 8; ++v) {
        const int src = 8 * jo + v;  // owner lane of x[v][16*jo ..] (imm)
        f32x2 a2 = acc2[v];
#pragma unroll
        for (int ci = 0; ci < 8; ++ci) {
          // d = 16*jo + 2*ci, d+1 — ascending-d chain per half (== R8)
          const float s0 = rdlane_f(xs[2 * ci], src);
          const float s1 = rdlane_f(xs[2 * ci + 1], src);
          f32x2 b0; b0[0] = pc[ci].x; b0[1] = pc[ci].y;
          f32x2 b1; b1[0] = pc[ci].z; b1[1] = pc[ci].w;
          f32x2 sv0; sv0[0] = s0; sv0[1] = s0;
          f32x2 sv1; sv1[0] = s1; sv1[1] = s1;
          a2 = __builtin_elementwise_fma(sv0, b0, a2);
          a2 = __builtin_elementwise_fma(sv1, b1, a2);
        }
        acc2[v] = a2;
      }
    }

    // ---- signs (ballot), norm/x0 (DPP reduce — R9/R10-proven) ----
    ull bl[8], bh[8];
    float n16v[8], x0v[8];
#pragma unroll
    for (int v = 0; v < 8; ++v) {
      bl[v] = __ballot(acc2[v][0] >= 0.0f);
      bh[v] = __ballot(acc2[v][1] >= 0.0f);
      const float a1 = fabsf(acc2[v][0]);
      const float a2 = fabsf(acc2[v][1]);
      const float s1 = wave_sum(a1 + a2);
      const float n2 = wave_sum(fmaf(a1, a1, a2 * a2));
      float norm = fmaxf(sqrtf(n2), 1e-8f);
      const float n16  = __half2float(__float2half(norm));
      const float x0   = s1 / (128.0f * norm);
      const float x016 = __half2float(__float2half(x0));
      n16v[v] = rfl_f(n16);
      x0v[v]  = rfl_f(x016);
    }

    // ---- store packed bytes / norms16 / x016 : R8 VERBATIM ----
    {
      const int s = lane & 7;
      const int jb = lane >> 3;
      const ull el = sel8_u64(bl, s);
      const ull eh = sel8_u64(bh, s);
      const float fl = (float)((unsigned)(el >> (8 * jb)) & 255u);
      const float fh = (float)((unsigned)(eh >> (8 * jb)) & 255u);
      out_pack[(size_t)(vbase + s) * 16 + jb] = fl;
      out_pack[(size_t)(vbase + s) * 16 + 8 + jb] = fh;
      if (lane < 16) {
        const float nsel = sel8_f(n16v, s);
        const float xsel = sel8_f(x0v, s);
        if (lane < 8) out_norm[vbase + s] = nsel;
        else          out_x0[vbase + s] = xsel;
      }
    }
  }
}

// ========================= Kernel B: dequantize (R8 VERBATIM) =========================
__global__ __launch_bounds__(256, 4) void rabitq_dequant(const float* __restrict__ Pm,
                                                         float* __restrict__ out) {
  __shared__ __align__(16) unsigned Bp[2048 * 4];  // 32 KiB bf16 B-frags

  const int tid = threadIdx.x, lane = tid & 63, ww = tid >> 6;
  const int l15 = lane & 15, lg = lane >> 4;

#pragma unroll
  for (int i = 0; i < 8; ++i) {
    const int s = tid + i * 256;
    const int ks = s >> 9, n = (s >> 6) & 7, l = s & 63;
    const int kb = ks * 32 + (l >> 4) * 8;
    const int f = n * 16 + (l & 15);
    u32x4v wv;
#pragma unroll
    for (int u = 0; u < 4; ++u) {
      const float p0 = Pm[(size_t)(kb + 2 * u) * 128 + f];
      const float p1 = Pm[(size_t)(kb + 2 * u + 1) * 128 + f];
      wv[u] = (unsigned)f2bf(p0) | ((unsigned)f2bf(p1) << 16);
    }
    *(u32x4v*)(&Bp[s * 4]) = wv;
  }
  __syncthreads();

  const float* const out_pack = out + (size_t)NVEC_TOTAL * 128;
  const float* const out_norm = out_pack + (size_t)NVEC_TOTAL * 16;
  const float* const out_x0   = out_norm + NVEC_TOTAL;

#pragma unroll 1
  for (int t = 0; t < 4; ++t) {
    const int vbase = (blockIdx.x * 4 + ww) * 64 + t * 16;
    const int vec = vbase + l15;

    const float* pb = out_pack + (size_t)vec * 16;
    const float4 b0 = *(const float4*)(pb + 0);
    const float4 b1 = *(const float4*)(pb + 4);
    const float4 b2 = *(const float4*)(pb + 8);
    const float4 b3 = *(const float4*)(pb + 12);
    unsigned mw[4];
    mw[0] = (unsigned)b0.x | ((unsigned)b0.y << 8) | ((unsigned)b0.z << 16) | ((unsigned)b0.w << 24);
    mw[1] = (unsigned)b1.x | ((unsigned)b1.y << 8) | ((unsigned)b1.z << 16) | ((unsigned)b1.w << 24);
    mw[2] = (unsigned)b2.x | ((unsigned)b2.y << 8) | ((unsigned)b2.z << 16) | ((unsigned)b2.w << 24);
    mw[3] = (unsigned)b3.x | ((unsigned)b3.y << 8) | ((unsigned)b3.z << 16) | ((unsigned)b3.w << 24);

    short8 a8[4];
#pragma unroll
    for (int ks = 0; ks < 4; ++ks) {
      const unsigned nb = (~mw[ks]) >> (lg * 8);
      u32x4v ta;
      ta[0] = 0x3F803F80u | ((nb & 1u) << 15)        | ((nb & 2u) << 30);
      ta[1] = 0x3F803F80u | (((nb >> 2) & 1u) << 15) | (((nb >> 2) & 2u) << 30);
      ta[2] = 0x3F803F80u | (((nb >> 4) & 1u) << 15) | (((nb >> 4) & 2u) << 30);
      ta[3] = 0x3F803F80u | (((nb >> 6) & 1u) << 15) | (((nb >> 6) & 2u) << 30);
      a8[ks] = __builtin_bit_cast(short8, ta);
    }

    f32x4 dacc[8];
#pragma unroll
    for (int n = 0; n < 8; ++n) { dacc[n][0] = 0.f; dacc[n][1] = 0.f; dacc[n][2] = 0.f; dacc[n][3] = 0.f; }
#pragma unroll
    for (int n = 0; n < 8; ++n) {
#pragma unroll
      for (int ks = 0; ks < 4; ++ks) {
        const short8 b8 = __builtin_bit_cast(short8, *(const u32x4v*)(&Bp[(ks * 512 + n * 64 + lane) * 4]));
        dacc[n] = __builtin_amdgcn_mfma_f32_16x16x32_bf16(a8[ks], b8, dacc[n], 0, 0, 0);
      }
    }

#pragma unroll
    for (int r = 0; r < 4; ++r) {
      const int row = vbase + lg * 4 + r;
      const float sc = out_norm[row] * out_x0[row];
      float* op = out + (size_t)row * 128 + l15;
#pragma unroll
      for (int n = 0; n < 8; ++n) op[n * 16] = sc * dacc[n][r];
    }
  }
}

extern "C" void kernel_launch(void* const* d_in, const int* in_sizes, int n_in,
                              void* d_out, int out_size, void* d_ws, size_t ws_size,
                              hipStream_t stream) {
  const float* x  = (const float*)d_in[0];
  const float* Pm = (const float*)d_in[1];
  float* out = (float*)d_out;
  // A: 262144 vec / (8 waves * 4 passes * 8 vec) = 1024 blocks; 64K LDS -> 2 blocks/CU.
  hipLaunchKernelGGL(rabitq_quant, dim3(1024), dim3(512), 0, stream, x, Pm, out);
  // B: 262144 vec / (4 waves * 4 passes * 16 vec) = 1024 blocks, exact cover.
  hipLaunchKernelGGL(rabitq_dequant, dim3(1024), dim3(256), 0, stream, Pm, out);
}

// Round 15
// 243.232 us; speedup vs baseline: 7.6670x; 7.6670x over previous
//
#include <hip/hip_runtime.h>
#include <hip/hip_fp16.h>

// RaBitQ forward, two kernels — ROUND-8 PROVEN STATE (243us), restored.
// x: 262144 vectors of D=128 fp32. P: 128x128 fp32 orthonormal.
// out f32 concat: x_hat[262144*128] | packed[262144*16] | norms16[262144] | x016[262144]
//
// Why this is the keeper: with lane = rotated-coord (required for the
// fp32 exact-order sign chain that matches np bit-for-bit), x must be
// broadcast through the per-CU LDS pipe: 40 b128/vec x ~12cyc x 1024 vec/CU
// = ~205us — R8's measured 198us quant IS that floor. All off-LDS delivery
// attempts (SMEM s_load, readlane, pinned-VGPR panels) were defeated by the
// compiler (remat R6, spill R12/R14, occupancy R13); bf16 MFMA rotation is
// ruled out numerically (~3000 borderline sign flips vs zero tolerance).
//
// Kernel A (quantize): LDS fp32 P swizzled; reg-staged x -> wave-private LDS
//   slot (T14); ascending-d fmaf chain -> signs bit-identical to np ref.
// Kernel B (dequantize): x_hat = (n16*x016) * (S @ bf16(P)) via MFMA.

#define NVEC_TOTAL (4 * 16 * 4096)
#define ROUNDS 4

typedef short short8 __attribute__((ext_vector_type(8)));
typedef float f32x4 __attribute__((ext_vector_type(4)));
typedef unsigned int u32x4v __attribute__((ext_vector_type(4)));
typedef unsigned long long ull;

__device__ __forceinline__ float rfl_f(float v) {
  return __int_as_float(__builtin_amdgcn_readfirstlane(__float_as_int(v)));
}

__device__ __forceinline__ ull sel8_u64(const ull* a, int s) {
  ull r0 = (s & 1) ? a[1] : a[0];
  ull r1 = (s & 1) ? a[3] : a[2];
  ull r2 = (s & 1) ? a[5] : a[4];
  ull r3 = (s & 1) ? a[7] : a[6];
  ull r4 = (s & 2) ? r1 : r0;
  ull r5 = (s & 2) ? r3 : r2;
  return (s & 4) ? r5 : r4;
}

__device__ __forceinline__ float sel8_f(const float* a, int s) {
  float r0 = (s & 1) ? a[1] : a[0];
  float r1 = (s & 1) ? a[3] : a[2];
  float r2 = (s & 1) ? a[5] : a[4];
  float r3 = (s & 1) ? a[7] : a[6];
  float r4 = (s & 2) ? r1 : r0;
  float r5 = (s & 2) ? r3 : r2;
  return (s & 4) ? r5 : r4;
}

__device__ __forceinline__ unsigned short f2bf(float f) {  // fp32 -> bf16 RNE
  unsigned u = __float_as_uint(f);
  return (unsigned short)((u + 0x7FFFu + ((u >> 16) & 1u)) >> 16);
}

// ========================= Kernel A: quantize =========================
__global__ __launch_bounds__(1024, 4) void rabitq_quant(const float* __restrict__ x,
                                                        const float* __restrict__ Pm,
                                                        float* __restrict__ out) {
  extern __shared__ __align__(16) char smem[];
  float* const Pl = (float*)smem;     // 64 KiB swizzled fp32 P
  char* const xs = smem + 65536;      // 16 wave-slots x 4 KiB

  const int tid = threadIdx.x;
  const int lane = tid & 63;
  const int ww = tid >> 6;

  // ---- stage P into LDS, swizzled (16B blocks, j ^ (row&7)) ----
  {
    const int r = tid >> 3;        // row 0..127, eight threads per row
    const int q = tid & 7;
#pragma unroll
    for (int c = 0; c < 4; ++c) {
      const int dd = q * 16 + c * 4;
      const int sj = (((dd >> 2) ^ (r & 7)) << 2);
      const float4 v = *(const float4*)(Pm + (size_t)r * 128 + dd);
      *(float4*)(&Pl[r * 128 + sj]) = v;
    }
  }
  __syncthreads();

  const int w = blockIdx.x * 16 + ww;  // global wave id, 0..8191
  float* const out_pack = out + (size_t)NVEC_TOTAL * 128;
  float* const out_norm = out_pack + (size_t)NVEC_TOTAL * 16;
  float* const out_x0   = out_norm + NVEC_TOTAL;

  const int sw1 = lane & 7;            // row-swizzle key
  float* const xb = (float*)(xs + ww * 4096);  // wave-private slot [8 vec][128 f]
  const int lsub = (lane >> 5);        // which of the 2 vectors per issue
  const int lcol = (lane & 31) * 4;    // float offset within vector

  // ---- prologue: load pass-0 x into regs (per-lane, coalesced) ----
  float4 pf0, pf1, pf2, pf3;
  {
    const int vb = w * 32;
    pf0 = *(const float4*)(x + (size_t)(vb + 0 + lsub) * 128 + lcol);
    pf1 = *(const float4*)(x + (size_t)(vb + 2 + lsub) * 128 + lcol);
    pf2 = *(const float4*)(x + (size_t)(vb + 4 + lsub) * 128 + lcol);
    pf3 = *(const float4*)(x + (size_t)(vb + 6 + lsub) * 128 + lcol);
  }

#pragma unroll 1
  for (int t = 0; t < ROUNDS; ++t) {
    const int vbase = w * 32 + t * 8;

    // ---- write staged regs to wave slot (canonical b128 pattern) ----
    {
      char* const dst = (char*)xb + lane * 16;
      *(float4*)(dst + 0)    = pf0;
      *(float4*)(dst + 1024) = pf1;
      *(float4*)(dst + 2048) = pf2;
      *(float4*)(dst + 3072) = pf3;
    }

    // ---- prefetch next pass's x into regs (latency hides under compute) ----
    if (t + 1 < ROUNDS) {
      const int vb = w * 32 + (t + 1) * 8;
      pf0 = *(const float4*)(x + (size_t)(vb + 0 + lsub) * 128 + lcol);
      pf1 = *(const float4*)(x + (size_t)(vb + 2 + lsub) * 128 + lcol);
      pf2 = *(const float4*)(x + (size_t)(vb + 4 + lsub) * 128 + lcol);
      pf3 = *(const float4*)(x + (size_t)(vb + 6 + lsub) * 128 + lcol);
    }

    // ---- x_rot = x @ P^T : ascending-d fmaf chain (signs proven vs np) ----
    float acc_lo[8], acc_hi[8];
#pragma unroll
    for (int v = 0; v < 8; ++v) { acc_lo[v] = 0.f; acc_hi[v] = 0.f; }

#pragma unroll 2
    for (int j = 0; j < 32; ++j) {
      const int js = ((j ^ sw1) << 2);
      const float4 pl = *(const float4*)(&Pl[lane * 128 + js]);
      const float4 ph = *(const float4*)(&Pl[(lane + 64) * 128 + js]);
#pragma unroll
      for (int v = 0; v < 8; ++v) {
        // wave-uniform LDS address -> broadcast, conflict-free
        const float4 xv = *(const float4*)(xb + v * 128 + j * 4);
        float al = acc_lo[v], ah = acc_hi[v];
        al = fmaf(xv.x, pl.x, al); ah = fmaf(xv.x, ph.x, ah);
        al = fmaf(xv.y, pl.y, al); ah = fmaf(xv.y, ph.y, ah);
        al = fmaf(xv.z, pl.z, al); ah = fmaf(xv.z, ph.z, ah);
        al = fmaf(xv.w, pl.w, al); ah = fmaf(xv.w, ph.w, ah);
        acc_lo[v] = al; acc_hi[v] = ah;
      }
    }

    // ---- signs, norm, x0 ----
    ull bl[8], bh[8];
    float n16v[8], x0v[8];
#pragma unroll
    for (int v = 0; v < 8; ++v) {
      bl[v] = __ballot(acc_lo[v] >= 0.0f);
      bh[v] = __ballot(acc_hi[v] >= 0.0f);
      const float a1 = fabsf(acc_lo[v]);
      const float a2 = fabsf(acc_hi[v]);
      float s1 = a1 + a2;
      float n2 = fmaf(a1, a1, a2 * a2);
#pragma unroll
      for (int off = 32; off > 0; off >>= 1) {
        s1 += __shfl_xor(s1, off);
        n2 += __shfl_xor(n2, off);
      }
      float norm = fmaxf(sqrtf(n2), 1e-8f);
      const float n16  = __half2float(__float2half(norm));
      const float x0   = s1 / (128.0f * norm);
      const float x016 = __half2float(__float2half(x0));
      n16v[v] = rfl_f(n16);
      x0v[v]  = rfl_f(x016);
    }

    // ---- store packed bytes / norms16 / x016 ----
    {
      const int s = lane & 7;
      const int jb = lane >> 3;
      const ull el = sel8_u64(bl, s);
      const ull eh = sel8_u64(bh, s);
      const float fl = (float)((unsigned)(el >> (8 * jb)) & 255u);
      const float fh = (float)((unsigned)(eh >> (8 * jb)) & 255u);
      out_pack[(size_t)(vbase + s) * 16 + jb] = fl;
      out_pack[(size_t)(vbase + s) * 16 + 8 + jb] = fh;
      if (lane < 16) {
        const float nsel = sel8_f(n16v, s);
        const float xsel = sel8_f(x0v, s);
        if (lane < 8) out_norm[vbase + s] = nsel;
        else          out_x0[vbase + s] = xsel;
      }
    }
  }
}

// ========================= Kernel B: dequantize =========================
__global__ __launch_bounds__(256, 4) void rabitq_dequant(const float* __restrict__ Pm,
                                                         float* __restrict__ out) {
  __shared__ __align__(16) unsigned Bp[2048 * 4];  // 32 KiB bf16 B-frags

  const int tid = threadIdx.x, lane = tid & 63, ww = tid >> 6;
  const int l15 = lane & 15, lg = lane >> 4;

#pragma unroll
  for (int i = 0; i < 8; ++i) {
    const int s = tid + i * 256;
    const int ks = s >> 9, n = (s >> 6) & 7, l = s & 63;
    const int kb = ks * 32 + (l >> 4) * 8;
    const int f = n * 16 + (l & 15);
    u32x4v wv;
#pragma unroll
    for (int u = 0; u < 4; ++u) {
      const float p0 = Pm[(size_t)(kb + 2 * u) * 128 + f];
      const float p1 = Pm[(size_t)(kb + 2 * u + 1) * 128 + f];
      wv[u] = (unsigned)f2bf(p0) | ((unsigned)f2bf(p1) << 16);
    }
    *(u32x4v*)(&Bp[s * 4]) = wv;
  }
  __syncthreads();

  const float* const out_pack = out + (size_t)NVEC_TOTAL * 128;
  const float* const out_norm = out_pack + (size_t)NVEC_TOTAL * 16;
  const float* const out_x0   = out_norm + NVEC_TOTAL;

#pragma unroll 1
  for (int t = 0; t < 4; ++t) {
    const int vbase = (blockIdx.x * 4 + ww) * 64 + t * 16;
    const int vec = vbase + l15;

    const float* pb = out_pack + (size_t)vec * 16;
    const float4 b0 = *(const float4*)(pb + 0);
    const float4 b1 = *(const float4*)(pb + 4);
    const float4 b2 = *(const float4*)(pb + 8);
    const float4 b3 = *(const float4*)(pb + 12);
    unsigned mw[4];
    mw[0] = (unsigned)b0.x | ((unsigned)b0.y << 8) | ((unsigned)b0.z << 16) | ((unsigned)b0.w << 24);
    mw[1] = (unsigned)b1.x | ((unsigned)b1.y << 8) | ((unsigned)b1.z << 16) | ((unsigned)b1.w << 24);
    mw[2] = (unsigned)b2.x | ((unsigned)b2.y << 8) | ((unsigned)b2.z << 16) | ((unsigned)b2.w << 24);
    mw[3] = (unsigned)b3.x | ((unsigned)b3.y << 8) | ((unsigned)b3.z << 16) | ((unsigned)b3.w << 24);

    short8 a8[4];
#pragma unroll
    for (int ks = 0; ks < 4; ++ks) {
      const unsigned nb = (~mw[ks]) >> (lg * 8);
      u32x4v ta;
      ta[0] = 0x3F803F80u | ((nb & 1u) << 15)        | ((nb & 2u) << 30);
      ta[1] = 0x3F803F80u | (((nb >> 2) & 1u) << 15) | (((nb >> 2) & 2u) << 30);
      ta[2] = 0x3F803F80u | (((nb >> 4) & 1u) << 15) | (((nb >> 4) & 2u) << 30);
      ta[3] = 0x3F803F80u | (((nb >> 6) & 1u) << 15) | (((nb >> 6) & 2u) << 30);
      a8[ks] = __builtin_bit_cast(short8, ta);
    }

    f32x4 dacc[8];
#pragma unroll
    for (int n = 0; n < 8; ++n) { dacc[n][0] = 0.f; dacc[n][1] = 0.f; dacc[n][2] = 0.f; dacc[n][3] = 0.f; }
#pragma unroll
    for (int n = 0; n < 8; ++n) {
#pragma unroll
      for (int ks = 0; ks < 4; ++ks) {
        const short8 b8 = __builtin_bit_cast(short8, *(const u32x4v*)(&Bp[(ks * 512 + n * 64 + lane) * 4]));
        dacc[n] = __builtin_amdgcn_mfma_f32_16x16x32_bf16(a8[ks], b8, dacc[n], 0, 0, 0);
      }
    }

#pragma unroll
    for (int r = 0; r < 4; ++r) {
      const int row = vbase + lg * 4 + r;
      const float sc = out_norm[row] * out_x0[row];
      float* op = out + (size_t)row * 128 + l15;
#pragma unroll
      for (int n = 0; n < 8; ++n) op[n * 16] = sc * dacc[n][r];
    }
  }
}

extern "C" void kernel_launch(void* const* d_in, const int* in_sizes, int n_in,
                              void* d_out, int out_size, void* d_ws, size_t ws_size,
                              hipStream_t stream) {
  const float* x  = (const float*)d_in[0];
  const float* Pm = (const float*)d_in[1];
  float* out = (float*)d_out;
  // A: 262144 vec / (16 waves * 4 rounds * 8 vec) = 512 blocks, exact cover.
  // Dynamic LDS: 64 KiB P + 16 waves * 4 KiB x = 128 KiB.
  hipLaunchKernelGGL(rabitq_quant, dim3(512), dim3(1024), 131072, stream, x, Pm, out);
  // B: 262144 vec / (4 waves * 4 passes * 16 vec) = 1024 blocks, exact cover.
  hipLaunchKernelGGL(rabitq_dequant, dim3(1024), dim3(256), 0, stream, Pm, out);
}